// Round 1
// baseline (283.098 us; speedup 1.0000x reference)
//
#include <hip/hip_runtime.h>
#include <hip/hip_bf16.h>
#include <stdint.h>

typedef __bf16 bf16_t;
typedef __bf16 bf16x8 __attribute__((ext_vector_type(8)));
typedef float f32x4 __attribute__((ext_vector_type(4)));

#define MFMA_16x16x32(A, B, C) __builtin_amdgcn_mfma_f32_16x16x32_bf16((A), (B), (C), 0, 0, 0)

// ---------- fp32 -> bf16 elementwise ----------
__global__ void k_cvt(const float* __restrict__ in, bf16_t* __restrict__ out, int n) {
  int i = blockIdx.x * blockDim.x + threadIdx.x;
  if (i < n) out[i] = (bf16_t)in[i];
}

// ---------- transpose + cast: in [C][N] f32 -> out [N][C] bf16, per batch (z) ----------
__global__ __launch_bounds__(256)
void k_transpose_cast(const float* __restrict__ in, bf16_t* __restrict__ out, int C, int N) {
  __shared__ float tile[32][33];
  int b = blockIdx.z;
  const float* src = in + (size_t)b * C * N;
  bf16_t* dst = out + (size_t)b * C * N;
  int n0 = blockIdx.x * 32, c0 = blockIdx.y * 32;
  int tx = threadIdx.x, ty = threadIdx.y;
#pragma unroll
  for (int i = 0; i < 32; i += 8)
    tile[ty + i][tx] = src[(size_t)(c0 + ty + i) * N + (n0 + tx)];
  __syncthreads();
#pragma unroll
  for (int i = 0; i < 32; i += 8)
    dst[(size_t)(n0 + ty + i) * C + (c0 + tx)] = (bf16_t)tile[tx][ty + i];
}

// ---------- C[M][N] = A[M][K] * B[N][K]^T  (bf16 in, fp32 acc) ----------
// 128x128 tile, BK=32, 4 waves (2x2), each wave 64x64 (4x4 frags of 16x16).
template <int OUT_BF16, int ADD_BIAS>
__global__ __launch_bounds__(256)
void k_gemm_bt(const bf16_t* __restrict__ A, const bf16_t* __restrict__ B,
               void* __restrict__ Cv, const float* __restrict__ bias,
               int M, int N, int K,
               long long sA, long long sB, long long sC) {
  const int b = blockIdx.z;
  A += (size_t)b * sA;
  B += (size_t)b * sB;
  const int tid = threadIdx.x;
  const int wave = tid >> 6, lane = tid & 63;
  const int l15 = lane & 15, l4 = lane >> 4;
  const int bm = blockIdx.y * 128, bn = blockIdx.x * 128;
  const int wm = (wave >> 1) * 64, wn = (wave & 1) * 64;

  __shared__ bf16_t As[128 * 32];
  __shared__ bf16_t Bs[128 * 32];

  f32x4 acc[4][4] = {};

  const int row_a = tid >> 2;        // rows tid>>2 and +64
  const int c8 = (tid & 3) * 8;      // 8-elem (16B) chunk within BK=32

  for (int k0 = 0; k0 < K; k0 += 32) {
    __syncthreads();
#pragma unroll
    for (int i = 0; i < 2; ++i) {
      int row = row_a + i * 64;
      *(uint4*)(&As[row * 32 + c8]) = *(const uint4*)(&A[(size_t)(bm + row) * K + k0 + c8]);
      *(uint4*)(&Bs[row * 32 + c8]) = *(const uint4*)(&B[(size_t)(bn + row) * K + k0 + c8]);
    }
    __syncthreads();
    bf16x8 af[4], bfr[4];
#pragma unroll
    for (int m = 0; m < 4; ++m)
      af[m] = *(const bf16x8*)(&As[(wm + m * 16 + l15) * 32 + l4 * 8]);
#pragma unroll
    for (int n = 0; n < 4; ++n)
      bfr[n] = *(const bf16x8*)(&Bs[(wn + n * 16 + l15) * 32 + l4 * 8]);
#pragma unroll
    for (int m = 0; m < 4; ++m)
#pragma unroll
      for (int n = 0; n < 4; ++n)
        acc[m][n] = MFMA_16x16x32(af[m], bfr[n], acc[m][n]);
  }

#pragma unroll
  for (int m = 0; m < 4; ++m) {
    const int row0 = bm + wm + m * 16 + l4 * 4;
#pragma unroll
    for (int n = 0; n < 4; ++n) {
      const int col = bn + wn + n * 16 + l15;
#pragma unroll
      for (int j = 0; j < 4; ++j) {
        float v = acc[m][n][j];
        if (OUT_BF16) {
          ((bf16_t*)Cv + (size_t)b * sC)[(size_t)(row0 + j) * N + col] = (bf16_t)v;
        } else {
          float o = v + (ADD_BIAS ? bias[row0 + j] : 0.0f);
          ((float*)Cv + (size_t)b * sC)[(size_t)(row0 + j) * N + col] = o;
        }
      }
    }
  }
}

// ---------- dots + softmax: one block per (b,h) ----------
// dots[i][j] = scale * sum_n q[hi][n] k[hj][n]; softmax over j; attn bf16 [bh][64][64]
__global__ __launch_bounds__(256)
void k_attn_scores(const bf16_t* __restrict__ q, const bf16_t* __restrict__ k,
                   bf16_t* __restrict__ attn) {
  const int bh = blockIdx.x;
  const bf16_t* qh = q + (size_t)(bh >> 3) * 512 * 4096 + (size_t)(bh & 7) * 64 * 4096;
  const bf16_t* kh = k + (size_t)(bh >> 3) * 512 * 4096 + (size_t)(bh & 7) * 64 * 4096;
  const int tid = threadIdx.x;
  const int wave = tid >> 6, lane = tid & 63;
  const int l15 = lane & 15, l4 = lane >> 4;
  const int wm = (wave >> 1) * 32, wn = (wave & 1) * 32;

  f32x4 acc[2][2] = {};
  for (int k0 = 0; k0 < 4096; k0 += 32) {
    bf16x8 af[2], bfr[2];
#pragma unroll
    for (int m = 0; m < 2; ++m)
      af[m] = *(const bf16x8*)(&qh[(size_t)(wm + m * 16 + l15) * 4096 + k0 + l4 * 8]);
#pragma unroll
    for (int n = 0; n < 2; ++n)
      bfr[n] = *(const bf16x8*)(&kh[(size_t)(wn + n * 16 + l15) * 4096 + k0 + l4 * 8]);
#pragma unroll
    for (int m = 0; m < 2; ++m)
#pragma unroll
      for (int n = 0; n < 2; ++n)
        acc[m][n] = MFMA_16x16x32(af[m], bfr[n], acc[m][n]);
  }

  __shared__ float S[64][65];
  const float scale = 0.125f;  // 1/sqrt(64)
#pragma unroll
  for (int m = 0; m < 2; ++m)
#pragma unroll
    for (int n = 0; n < 2; ++n)
#pragma unroll
      for (int j = 0; j < 4; ++j)
        S[wm + m * 16 + l4 * 4 + j][wn + n * 16 + l15] = acc[m][n][j] * scale;
  __syncthreads();

  // row softmax: 4 threads per row (consecutive lanes), 16 cols each
  const int r = tid >> 2, seg = (tid & 3) * 16;
  float vals[16];
  float mx = -1e30f;
#pragma unroll
  for (int c = 0; c < 16; ++c) { vals[c] = S[r][seg + c]; mx = fmaxf(mx, vals[c]); }
  mx = fmaxf(mx, __shfl_xor(mx, 1));
  mx = fmaxf(mx, __shfl_xor(mx, 2));
  float sum = 0.f;
#pragma unroll
  for (int c = 0; c < 16; ++c) { vals[c] = __expf(vals[c] - mx); sum += vals[c]; }
  sum += __shfl_xor(sum, 1);
  sum += __shfl_xor(sum, 2);
  const float inv = 1.0f / sum;
  bf16_t* arow = attn + (size_t)bh * 64 * 64 + (size_t)r * 64 + seg;
#pragma unroll
  for (int c = 0; c < 16; ++c) arow[c] = (bf16_t)(vals[c] * inv);
}

// ---------- outT[n][h*64+i] = sum_j vT[n][h*64+j] * attn[i][j] ----------
// grid (n-blocks of 128, bh); 4 waves: wave w rows r0=w*32 (2 m-frags), 64 cols (4 n-frags), K=64
__global__ __launch_bounds__(256)
void k_attn_apply(const bf16_t* __restrict__ vT, const bf16_t* __restrict__ attn,
                  bf16_t* __restrict__ outT) {
  const int bh = blockIdx.y;
  const int b = bh >> 3, h = bh & 7;
  const int tid = threadIdx.x;
  const int wave = tid >> 6, lane = tid & 63;
  const int l15 = lane & 15, l4 = lane >> 4;
  const bf16_t* vb = vT + (size_t)b * 4096 * 512 + h * 64;
  const bf16_t* ab = attn + (size_t)bh * 64 * 64;
  bf16_t* ob = outT + (size_t)b * 4096 * 512 + h * 64;
  const int r0 = blockIdx.x * 128 + wave * 32;

  f32x4 acc[2][4] = {};
#pragma unroll
  for (int ks = 0; ks < 2; ++ks) {
    const int k0 = ks * 32;
    bf16x8 af[2], bfr[4];
#pragma unroll
    for (int m = 0; m < 2; ++m)
      af[m] = *(const bf16x8*)(&vb[(size_t)(r0 + m * 16 + l15) * 512 + k0 + l4 * 8]);
#pragma unroll
    for (int n = 0; n < 4; ++n)
      bfr[n] = *(const bf16x8*)(&ab[(n * 16 + l15) * 64 + k0 + l4 * 8]);
#pragma unroll
    for (int m = 0; m < 2; ++m)
#pragma unroll
      for (int n = 0; n < 4; ++n)
        acc[m][n] = MFMA_16x16x32(af[m], bfr[n], acc[m][n]);
  }
#pragma unroll
  for (int m = 0; m < 2; ++m)
#pragma unroll
    for (int n = 0; n < 4; ++n)
#pragma unroll
      for (int j = 0; j < 4; ++j)
        ob[(size_t)(r0 + m * 16 + l4 * 4 + j) * 512 + n * 16 + l15] = (bf16_t)acc[m][n][j];
}

extern "C" void kernel_launch(void* const* d_in, const int* in_sizes, int n_in,
                              void* d_out, int out_size, void* d_ws, size_t ws_size,
                              hipStream_t stream) {
  const float* f_m  = (const float*)d_in[0];
  const float* f_n  = (const float*)d_in[1];
  const float* Wq   = (const float*)d_in[2];
  const float* Wkv  = (const float*)d_in[3];
  const float* Wout = (const float*)d_in[4];
  const float* bout = (const float*)d_in[5];
  float* y = (float*)d_out;

  const size_t ACT = (size_t)8 * 4096 * 512;  // elements per [b][4096][512] tensor
  char* p = (char*)d_ws;
  bf16_t* wq_b   = (bf16_t*)p; p += (size_t)512 * 512 * 2;
  bf16_t* wkv_b  = (bf16_t*)p; p += (size_t)1024 * 512 * 2;
  bf16_t* wout_b = (bf16_t*)p; p += (size_t)512 * 512 * 2;
  bf16_t* attnw  = (bf16_t*)p; p += (size_t)64 * 64 * 64 * 2;
  bf16_t* fmT    = (bf16_t*)p; p += ACT * 2;
  bf16_t* fnT    = (bf16_t*)p; p += ACT * 2;
  bf16_t* qb     = (bf16_t*)p; p += ACT * 2;
  bf16_t* kb     = (bf16_t*)p; p += ACT * 2;
  bf16_t* vT     = (bf16_t*)p; p += ACT * 2;
  bf16_t* outT   = fmT;  // fmT dead after q projection

  k_cvt<<<dim3((512 * 512 + 255) / 256), 256, 0, stream>>>(Wq, wq_b, 512 * 512);
  k_cvt<<<dim3((1024 * 512 + 255) / 256), 256, 0, stream>>>(Wkv, wkv_b, 1024 * 512);
  k_cvt<<<dim3((512 * 512 + 255) / 256), 256, 0, stream>>>(Wout, wout_b, 512 * 512);

  k_transpose_cast<<<dim3(128, 16, 8), dim3(32, 8), 0, stream>>>(f_m, fmT, 512, 4096);
  k_transpose_cast<<<dim3(128, 16, 8), dim3(32, 8), 0, stream>>>(f_n, fnT, 512, 4096);

  const long long sAct = (long long)4096 * 512;
  // q[b][o][n] = Wq . fmT^T
  k_gemm_bt<1, 0><<<dim3(32, 4, 8), 256, 0, stream>>>(wq_b, fmT, qb, nullptr,
                                                      512, 4096, 512, 0, sAct, sAct);
  // k[b][o][n] = Wk . fnT^T   (Wk = rows 0..511 of Wkv)
  k_gemm_bt<1, 0><<<dim3(32, 4, 8), 256, 0, stream>>>(wkv_b, fnT, kb, nullptr,
                                                      512, 4096, 512, 0, sAct, sAct);
  // vT[b][n][o] = fnT . Wv^T  (Wv = rows 512..1023 of Wkv)
  k_gemm_bt<1, 0><<<dim3(4, 32, 8), 256, 0, stream>>>(fnT, wkv_b + (size_t)512 * 512, vT, nullptr,
                                                      4096, 512, 512, sAct, 0, sAct);
  // attn[bh][64][64]
  k_attn_scores<<<dim3(64), 256, 0, stream>>>(qb, kb, attnw);
  // outT[b][n][512]
  k_attn_apply<<<dim3(32, 64), 256, 0, stream>>>(vT, attnw, outT);
  // y[b][o][n] = Wout . outT^T + bout
  k_gemm_bt<0, 1><<<dim3(32, 4, 8), 256, 0, stream>>>(wout_b, outT, y, bout,
                                                      512, 4096, 512, 0, sAct, sAct);
}

// Round 2
// 237.276 us; speedup vs baseline: 1.1931x; 1.1931x over previous
//
#include <hip/hip_runtime.h>
#include <hip/hip_bf16.h>
#include <stdint.h>

typedef __bf16 bf16_t;
typedef __bf16 bf16x8 __attribute__((ext_vector_type(8)));
typedef float f32x4 __attribute__((ext_vector_type(4)));

#define MFMA_16x16x32(A, B, C) __builtin_amdgcn_mfma_f32_16x16x32_bf16((A), (B), (C), 0, 0, 0)

// ---------- fp32 -> bf16 elementwise ----------
__global__ void k_cvt(const float* __restrict__ in, bf16_t* __restrict__ out, int n) {
  int i = blockIdx.x * blockDim.x + threadIdx.x;
  if (i < n) out[i] = (bf16_t)in[i];
}

// ---------- transpose + cast: in [C][N] f32 -> out [N][C] bf16, per batch (z) ----------
__global__ __launch_bounds__(256)
void k_transpose_cast(const float* __restrict__ in, bf16_t* __restrict__ out, int C, int N) {
  __shared__ float tile[32][33];
  int b = blockIdx.z;
  const float* src = in + (size_t)b * C * N;
  bf16_t* dst = out + (size_t)b * C * N;
  int n0 = blockIdx.x * 32, c0 = blockIdx.y * 32;
  int tx = threadIdx.x, ty = threadIdx.y;
#pragma unroll
  for (int i = 0; i < 32; i += 8)
    tile[ty + i][tx] = src[(size_t)(c0 + ty + i) * N + (n0 + tx)];
  __syncthreads();
#pragma unroll
  for (int i = 0; i < 32; i += 8)
    dst[(size_t)(n0 + ty + i) * C + (c0 + tx)] = (bf16_t)tile[tx][ty + i];
}

// ---------- C[M][N] = A[M][K] * B[N][K]^T  (bf16 in, fp32 acc) ----------
// 128x128 tile, BK=32, 4 waves (2x2), each wave 64x64 (4x4 frags of 16x16).
template <int OUT_BF16, int ADD_BIAS>
__global__ __launch_bounds__(256)
void k_gemm_bt(const bf16_t* __restrict__ A, const bf16_t* __restrict__ B,
               void* __restrict__ Cv, const float* __restrict__ bias,
               int M, int N, int K,
               long long sA, long long sB, long long sC) {
  const int b = blockIdx.z;
  A += (size_t)b * sA;
  B += (size_t)b * sB;
  const int tid = threadIdx.x;
  const int wave = tid >> 6, lane = tid & 63;
  const int l15 = lane & 15, l4 = lane >> 4;
  const int bm = blockIdx.y * 128, bn = blockIdx.x * 128;
  const int wm = (wave >> 1) * 64, wn = (wave & 1) * 64;

  __shared__ bf16_t As[128 * 32];
  __shared__ bf16_t Bs[128 * 32];

  f32x4 acc[4][4] = {};

  const int row_a = tid >> 2;        // rows tid>>2 and +64
  const int c8 = (tid & 3) * 8;      // 8-elem (16B) chunk within BK=32

  for (int k0 = 0; k0 < K; k0 += 32) {
    __syncthreads();
#pragma unroll
    for (int i = 0; i < 2; ++i) {
      int row = row_a + i * 64;
      *(uint4*)(&As[row * 32 + c8]) = *(const uint4*)(&A[(size_t)(bm + row) * K + k0 + c8]);
      *(uint4*)(&Bs[row * 32 + c8]) = *(const uint4*)(&B[(size_t)(bn + row) * K + k0 + c8]);
    }
    __syncthreads();
    bf16x8 af[4], bfr[4];
#pragma unroll
    for (int m = 0; m < 4; ++m)
      af[m] = *(const bf16x8*)(&As[(wm + m * 16 + l15) * 32 + l4 * 8]);
#pragma unroll
    for (int n = 0; n < 4; ++n)
      bfr[n] = *(const bf16x8*)(&Bs[(wn + n * 16 + l15) * 32 + l4 * 8]);
#pragma unroll
    for (int m = 0; m < 4; ++m)
#pragma unroll
      for (int n = 0; n < 4; ++n)
        acc[m][n] = MFMA_16x16x32(af[m], bfr[n], acc[m][n]);
  }

#pragma unroll
  for (int m = 0; m < 4; ++m) {
    const int row0 = bm + wm + m * 16 + l4 * 4;
#pragma unroll
    for (int n = 0; n < 4; ++n) {
      const int col = bn + wn + n * 16 + l15;
#pragma unroll
      for (int j = 0; j < 4; ++j) {
        float v = acc[m][n][j];
        if (OUT_BF16) {
          ((bf16_t*)Cv + (size_t)b * sC)[(size_t)(row0 + j) * N + col] = (bf16_t)v;
        } else {
          float o = v + (ADD_BIAS ? bias[row0 + j] : 0.0f);
          ((float*)Cv + (size_t)b * sC)[(size_t)(row0 + j) * N + col] = o;
        }
      }
    }
  }
}

// ---------- dots partial: grid (ksplit=16, bh=64) ----------
// partial[bh][ks][64][64] = sum over n in [ks*256, ks*256+256) of q[i][n]*k[j][n]
__global__ __launch_bounds__(256)
void k_dots_partial(const bf16_t* __restrict__ q, const bf16_t* __restrict__ k,
                    float* __restrict__ partial) {
  const int ks = blockIdx.x, bh = blockIdx.y;
  const bf16_t* qh = q + (size_t)(bh >> 3) * 512 * 4096 + (size_t)(bh & 7) * 64 * 4096;
  const bf16_t* kh = k + (size_t)(bh >> 3) * 512 * 4096 + (size_t)(bh & 7) * 64 * 4096;
  const int tid = threadIdx.x;
  const int wave = tid >> 6, lane = tid & 63;
  const int l15 = lane & 15, l4 = lane >> 4;
  const int wm = (wave >> 1) * 32, wn = (wave & 1) * 32;
  const int n0 = ks * 256;

  f32x4 acc[2][2] = {};
#pragma unroll 2
  for (int k0 = n0; k0 < n0 + 256; k0 += 32) {
    bf16x8 af[2], bfr[2];
#pragma unroll
    for (int m = 0; m < 2; ++m)
      af[m] = *(const bf16x8*)(&qh[(size_t)(wm + m * 16 + l15) * 4096 + k0 + l4 * 8]);
#pragma unroll
    for (int n = 0; n < 2; ++n)
      bfr[n] = *(const bf16x8*)(&kh[(size_t)(wn + n * 16 + l15) * 4096 + k0 + l4 * 8]);
#pragma unroll
    for (int m = 0; m < 2; ++m)
#pragma unroll
      for (int n = 0; n < 2; ++n)
        acc[m][n] = MFMA_16x16x32(af[m], bfr[n], acc[m][n]);
  }

  float* pp = partial + (size_t)bh * 16 * 4096 + (size_t)ks * 4096;
#pragma unroll
  for (int m = 0; m < 2; ++m)
#pragma unroll
    for (int n = 0; n < 2; ++n)
#pragma unroll
      for (int j = 0; j < 4; ++j)
        pp[(size_t)(wm + m * 16 + l4 * 4 + j) * 64 + wn + n * 16 + l15] = acc[m][n][j];
}

// ---------- reduce partials + softmax -> attn bf16 [bh][64][64] ----------
__global__ __launch_bounds__(256)
void k_softmax(const float* __restrict__ partial, bf16_t* __restrict__ attn) {
  const int bh = blockIdx.x;
  const float* p = partial + (size_t)bh * 16 * 4096;
  const int tid = threadIdx.x;
  const int r = tid >> 2, seg = (tid & 3) * 16;
  const float scale = 0.125f;  // 1/sqrt(64)

  float vals[16] = {};
#pragma unroll
  for (int ks = 0; ks < 16; ++ks) {
    const float* row = p + (size_t)ks * 4096 + (size_t)r * 64 + seg;
#pragma unroll
    for (int c = 0; c < 16; c += 4) {
      float4 v4 = *(const float4*)(row + c);
      vals[c] += v4.x; vals[c + 1] += v4.y; vals[c + 2] += v4.z; vals[c + 3] += v4.w;
    }
  }
  float mx = -1e30f;
#pragma unroll
  for (int c = 0; c < 16; ++c) { vals[c] *= scale; mx = fmaxf(mx, vals[c]); }
  mx = fmaxf(mx, __shfl_xor(mx, 1));
  mx = fmaxf(mx, __shfl_xor(mx, 2));
  float sum = 0.f;
#pragma unroll
  for (int c = 0; c < 16; ++c) { vals[c] = __expf(vals[c] - mx); sum += vals[c]; }
  sum += __shfl_xor(sum, 1);
  sum += __shfl_xor(sum, 2);
  const float inv = 1.0f / sum;
  bf16_t* arow = attn + (size_t)bh * 64 * 64 + (size_t)r * 64 + seg;
#pragma unroll
  for (int c = 0; c < 16; ++c) arow[c] = (bf16_t)(vals[c] * inv);
}

// ---------- outT[n][h*64+i] = sum_j vT[n][h*64+j] * attn[i][j] ----------
__global__ __launch_bounds__(256)
void k_attn_apply(const bf16_t* __restrict__ vT, const bf16_t* __restrict__ attn,
                  bf16_t* __restrict__ outT) {
  const int bh = blockIdx.y;
  const int b = bh >> 3, h = bh & 7;
  const int tid = threadIdx.x;
  const int wave = tid >> 6, lane = tid & 63;
  const int l15 = lane & 15, l4 = lane >> 4;
  const bf16_t* vb = vT + (size_t)b * 4096 * 512 + h * 64;
  const bf16_t* ab = attn + (size_t)bh * 64 * 64;
  bf16_t* ob = outT + (size_t)b * 4096 * 512 + h * 64;
  const int r0 = blockIdx.x * 128 + wave * 32;

  f32x4 acc[2][4] = {};
#pragma unroll
  for (int ks = 0; ks < 2; ++ks) {
    const int k0 = ks * 32;
    bf16x8 af[2], bfr[4];
#pragma unroll
    for (int m = 0; m < 2; ++m)
      af[m] = *(const bf16x8*)(&vb[(size_t)(r0 + m * 16 + l15) * 512 + k0 + l4 * 8]);
#pragma unroll
    for (int n = 0; n < 4; ++n)
      bfr[n] = *(const bf16x8*)(&ab[(n * 16 + l15) * 64 + k0 + l4 * 8]);
#pragma unroll
    for (int m = 0; m < 2; ++m)
#pragma unroll
      for (int n = 0; n < 4; ++n)
        acc[m][n] = MFMA_16x16x32(af[m], bfr[n], acc[m][n]);
  }
#pragma unroll
  for (int m = 0; m < 2; ++m)
#pragma unroll
    for (int n = 0; n < 4; ++n)
#pragma unroll
      for (int j = 0; j < 4; ++j)
        ob[(size_t)(r0 + m * 16 + l4 * 4 + j) * 512 + n * 16 + l15] = (bf16_t)acc[m][n][j];
}

extern "C" void kernel_launch(void* const* d_in, const int* in_sizes, int n_in,
                              void* d_out, int out_size, void* d_ws, size_t ws_size,
                              hipStream_t stream) {
  const float* f_m  = (const float*)d_in[0];
  const float* f_n  = (const float*)d_in[1];
  const float* Wq   = (const float*)d_in[2];
  const float* Wkv  = (const float*)d_in[3];
  const float* Wout = (const float*)d_in[4];
  const float* bout = (const float*)d_in[5];
  float* y = (float*)d_out;

  const size_t ACT = (size_t)8 * 4096 * 512;  // elements per [b][4096][512] tensor
  char* p = (char*)d_ws;
  bf16_t* wq_b   = (bf16_t*)p; p += (size_t)512 * 512 * 2;
  bf16_t* wkv_b  = (bf16_t*)p; p += (size_t)1024 * 512 * 2;
  bf16_t* wout_b = (bf16_t*)p; p += (size_t)512 * 512 * 2;
  bf16_t* attnw  = (bf16_t*)p; p += (size_t)64 * 64 * 64 * 2;
  float*  dotsp  = (float*)p;  p += (size_t)64 * 16 * 4096 * 4;  // 16 MB partials
  bf16_t* fmT    = (bf16_t*)p; p += ACT * 2;
  bf16_t* fnT    = (bf16_t*)p; p += ACT * 2;
  bf16_t* qb     = (bf16_t*)p; p += ACT * 2;
  bf16_t* kb     = (bf16_t*)p; p += ACT * 2;
  bf16_t* vT     = (bf16_t*)p; p += ACT * 2;
  bf16_t* outT   = fmT;  // fmT dead after q projection

  k_cvt<<<dim3((512 * 512 + 255) / 256), 256, 0, stream>>>(Wq, wq_b, 512 * 512);
  k_cvt<<<dim3((1024 * 512 + 255) / 256), 256, 0, stream>>>(Wkv, wkv_b, 1024 * 512);
  k_cvt<<<dim3((512 * 512 + 255) / 256), 256, 0, stream>>>(Wout, wout_b, 512 * 512);

  k_transpose_cast<<<dim3(128, 16, 8), dim3(32, 8), 0, stream>>>(f_m, fmT, 512, 4096);
  k_transpose_cast<<<dim3(128, 16, 8), dim3(32, 8), 0, stream>>>(f_n, fnT, 512, 4096);

  const long long sAct = (long long)4096 * 512;
  // q[b][o][n] = Wq . fmT^T
  k_gemm_bt<1, 0><<<dim3(32, 4, 8), 256, 0, stream>>>(wq_b, fmT, qb, nullptr,
                                                      512, 4096, 512, 0, sAct, sAct);
  // k[b][o][n] = Wk . fnT^T   (Wk = rows 0..511 of Wkv)
  k_gemm_bt<1, 0><<<dim3(32, 4, 8), 256, 0, stream>>>(wkv_b, fnT, kb, nullptr,
                                                      512, 4096, 512, 0, sAct, sAct);
  // vT[b][n][o] = fnT . Wv^T  (Wv = rows 512..1023 of Wkv)
  k_gemm_bt<1, 0><<<dim3(4, 32, 8), 256, 0, stream>>>(fnT, wkv_b + (size_t)512 * 512, vT, nullptr,
                                                      4096, 512, 512, sAct, 0, sAct);
  // dots partials then softmax -> attn[bh][64][64]
  k_dots_partial<<<dim3(16, 64), 256, 0, stream>>>(qb, kb, dotsp);
  k_softmax<<<dim3(64), 256, 0, stream>>>(dotsp, attnw);
  // outT[b][n][512]
  k_attn_apply<<<dim3(32, 64), 256, 0, stream>>>(vT, attnw, outT);
  // y[b][o][n] = Wout . outT^T + bout
  k_gemm_bt<0, 1><<<dim3(32, 4, 8), 256, 0, stream>>>(wout_b, outT, y, bout,
                                                      512, 4096, 512, 0, sAct, sAct);
}

// Round 3
// 186.247 us; speedup vs baseline: 1.5200x; 1.2740x over previous
//
#include <hip/hip_runtime.h>
#include <hip/hip_bf16.h>
#include <stdint.h>

typedef __bf16 bf16_t;
typedef __bf16 bf16x8 __attribute__((ext_vector_type(8)));
typedef float f32x4 __attribute__((ext_vector_type(4)));

#define MFMA_16x16x32(A, B, C) __builtin_amdgcn_mfma_f32_16x16x32_bf16((A), (B), (C), 0, 0, 0)

__device__ inline void gload_lds16(const bf16_t* g, bf16_t* lds) {
  auto* gp = (const __attribute__((address_space(1))) uint32_t*)(uintptr_t)g;
  auto* lp = (__attribute__((address_space(3))) uint32_t*)(uintptr_t)lds;
  __builtin_amdgcn_global_load_lds(gp, lp, 16, 0, 0);
}

// ---------- fp32 -> bf16 elementwise (scalar, for small weights) ----------
__global__ void k_cvt(const float* __restrict__ in, bf16_t* __restrict__ out, int n) {
  int i = blockIdx.x * blockDim.x + threadIdx.x;
  if (i < n) out[i] = (bf16_t)in[i];
}

// ---------- fp32 -> bf16, 4 elems/thread ----------
__global__ __launch_bounds__(256)
void k_cvt4(const float* __restrict__ in, bf16_t* __restrict__ out, int n4) {
  int i = blockIdx.x * blockDim.x + threadIdx.x;
  if (i < n4) {
    float4 v = *(const float4*)(in + (size_t)i * 4);
    bf16_t o[4] = {(bf16_t)v.x, (bf16_t)v.y, (bf16_t)v.z, (bf16_t)v.w};
    *(uint2*)(out + (size_t)i * 4) = *(uint2*)o;
  }
}

// ---------- transpose + cast: in [C][N] f32 -> out [N][C] bf16, per batch (z) ----------
__global__ __launch_bounds__(256)
void k_transpose_cast(const float* __restrict__ in, bf16_t* __restrict__ out, int C, int N) {
  __shared__ float tile[32][33];
  int b = blockIdx.z;
  const float* src = in + (size_t)b * C * N;
  bf16_t* dst = out + (size_t)b * C * N;
  int n0 = blockIdx.x * 32, c0 = blockIdx.y * 32;
  int tx = threadIdx.x, ty = threadIdx.y;
#pragma unroll
  for (int i = 0; i < 32; i += 8)
    tile[ty + i][tx] = src[(size_t)(c0 + ty + i) * N + (n0 + tx)];
  __syncthreads();
#pragma unroll
  for (int i = 0; i < 32; i += 8)
    dst[(size_t)(n0 + ty + i) * C + (c0 + tx)] = (bf16_t)tile[tx][ty + i];
}

// ---------- f_n prep: read f32 [C][N], write bf16 [C][N] AND bf16 [N][C] ----------
__global__ __launch_bounds__(256)
void k_prep_fn(const float* __restrict__ in, bf16_t* __restrict__ out_cn,
               bf16_t* __restrict__ out_nc, int C, int N) {
  __shared__ float tile[32][33];
  int b = blockIdx.z;
  const float* src = in + (size_t)b * C * N;
  bf16_t* dcn = out_cn + (size_t)b * C * N;
  bf16_t* dnc = out_nc + (size_t)b * C * N;
  int n0 = blockIdx.x * 32, c0 = blockIdx.y * 32;
  int tx = threadIdx.x, ty = threadIdx.y;
#pragma unroll
  for (int i = 0; i < 32; i += 8) {
    float v = src[(size_t)(c0 + ty + i) * N + (n0 + tx)];
    tile[ty + i][tx] = v;
    dcn[(size_t)(c0 + ty + i) * N + (n0 + tx)] = (bf16_t)v;
  }
  __syncthreads();
#pragma unroll
  for (int i = 0; i < 32; i += 8)
    dnc[(size_t)(n0 + ty + i) * C + (c0 + tx)] = (bf16_t)tile[tx][ty + i];
}

// ---------- C[M][N] = A[M][K] * B[N][K]^T  (bf16 in, fp32 acc), m97-staged ----------
// 128x128 tile, BK=32, 4 waves (2x2), each wave 64x64 (4x4 frags of 16x16).
// global_load_lds width-16 staging; optional split-K via KS (blockIdx.z = b*KS+ks).
// MODE: 0 = f32 out + bias, 1 = bf16 out, 2 = f32 partial (no bias)
template <int MODE>
__global__ __launch_bounds__(256)
void k_gemm_bt(const bf16_t* __restrict__ A, const bf16_t* __restrict__ B,
               void* __restrict__ Cv, const float* __restrict__ bias,
               int M, int N, int K, int KS,
               long long sA, long long sB, long long sC) {
  const int zb = blockIdx.z;
  const int b = zb / KS, ks = zb - b * KS;
  A += (size_t)b * sA;
  B += (size_t)b * sB;
  const int klen = K / KS;
  const int kbeg = ks * klen, kend = kbeg + klen;

  const int tid = threadIdx.x;
  const int wave = tid >> 6, lane = tid & 63;
  const int l15 = lane & 15, l4 = lane >> 4;
  const int bm = blockIdx.y * 128, bn = blockIdx.x * 128;
  const int wm = (wave >> 1) * 64, wn = (wave & 1) * 64;

  __shared__ bf16_t As[128 * 32];
  __shared__ bf16_t Bs[128 * 32];

  f32x4 acc[4][4] = {};

  const int lrow = lane >> 2;        // 0..15 within wave
  const int lchunk = (lane & 3) * 8; // elem offset within BK=32

  for (int k0 = kbeg; k0 < kend; k0 += 32) {
    __syncthreads();
    {
      const int ra = wave * 16 + lrow;
      gload_lds16(&A[(size_t)(bm + ra) * K + k0 + lchunk],      &As[(wave * 16) * 32]);
      gload_lds16(&A[(size_t)(bm + 64 + ra) * K + k0 + lchunk], &As[(64 + wave * 16) * 32]);
      gload_lds16(&B[(size_t)(bn + ra) * K + k0 + lchunk],      &Bs[(wave * 16) * 32]);
      gload_lds16(&B[(size_t)(bn + 64 + ra) * K + k0 + lchunk], &Bs[(64 + wave * 16) * 32]);
    }
    __syncthreads();
    bf16x8 af[4], bfr[4];
#pragma unroll
    for (int m = 0; m < 4; ++m)
      af[m] = *(const bf16x8*)(&As[(wm + m * 16 + l15) * 32 + l4 * 8]);
#pragma unroll
    for (int n = 0; n < 4; ++n)
      bfr[n] = *(const bf16x8*)(&Bs[(wn + n * 16 + l15) * 32 + l4 * 8]);
#pragma unroll
    for (int m = 0; m < 4; ++m)
#pragma unroll
      for (int n = 0; n < 4; ++n)
        acc[m][n] = MFMA_16x16x32(af[m], bfr[n], acc[m][n]);
  }

#pragma unroll
  for (int m = 0; m < 4; ++m) {
    const int row0 = bm + wm + m * 16 + l4 * 4;
#pragma unroll
    for (int n = 0; n < 4; ++n) {
      const int col = bn + wn + n * 16 + l15;
#pragma unroll
      for (int j = 0; j < 4; ++j) {
        float v = acc[m][n][j];
        if (MODE == 1) {
          ((bf16_t*)Cv + (size_t)zb * sC)[(size_t)(row0 + j) * N + col] = (bf16_t)v;
        } else if (MODE == 0) {
          ((float*)Cv + (size_t)zb * sC)[(size_t)(row0 + j) * N + col] = v + bias[row0 + j];
        } else {
          ((float*)Cv + (size_t)zb * sC)[(size_t)(row0 + j) * N + col] = v;
        }
      }
    }
  }
}

// ---------- reduce 4 split-K partials -> bf16 ----------
__global__ __launch_bounds__(256)
void k_reduce4(const float* __restrict__ p, bf16_t* __restrict__ out, int per_b) {
  // p layout: [b*4 + ks][per_b]; out: [b][per_b]; 4 elems per thread
  int i = blockIdx.x * blockDim.x + threadIdx.x;
  int nt4 = per_b / 4;
  int b = i / nt4, e4 = (i - b * nt4) * 4;
  const float* pb = p + (size_t)b * 4 * per_b + e4;
  float4 s = *(const float4*)(pb);
#pragma unroll
  for (int ks = 1; ks < 4; ++ks) {
    float4 v = *(const float4*)(pb + (size_t)ks * per_b);
    s.x += v.x; s.y += v.y; s.z += v.z; s.w += v.w;
  }
  bf16_t o[4] = {(bf16_t)s.x, (bf16_t)s.y, (bf16_t)s.z, (bf16_t)s.w};
  *(uint2*)(out + (size_t)b * per_b + e4) = *(uint2*)o;
}

// ---------- dots + softmax: one block per (b,h) ----------
// dots[i][j] = scale * sum_c T1[b][h*64+i][c] * Wk[h*64+j][c]; softmax over j
__global__ __launch_bounds__(256)
void k_dots_softmax(const bf16_t* __restrict__ T1, const bf16_t* __restrict__ wk,
                    bf16_t* __restrict__ attn) {
  const int bh = blockIdx.x;
  const bf16_t* qh = T1 + (size_t)(bh >> 3) * 262144 + (size_t)(bh & 7) * 64 * 512;
  const bf16_t* kh = wk + (size_t)(bh & 7) * 64 * 512;
  const int tid = threadIdx.x;
  const int wave = tid >> 6, lane = tid & 63;
  const int l15 = lane & 15, l4 = lane >> 4;
  const int wm = (wave >> 1) * 32, wn = (wave & 1) * 32;

  f32x4 acc[2][2] = {};
#pragma unroll 2
  for (int k0 = 0; k0 < 512; k0 += 32) {
    bf16x8 af[2], bfr[2];
#pragma unroll
    for (int m = 0; m < 2; ++m)
      af[m] = *(const bf16x8*)(&qh[(size_t)(wm + m * 16 + l15) * 512 + k0 + l4 * 8]);
#pragma unroll
    for (int n = 0; n < 2; ++n)
      bfr[n] = *(const bf16x8*)(&kh[(size_t)(wn + n * 16 + l15) * 512 + k0 + l4 * 8]);
#pragma unroll
    for (int m = 0; m < 2; ++m)
#pragma unroll
      for (int n = 0; n < 2; ++n)
        acc[m][n] = MFMA_16x16x32(af[m], bfr[n], acc[m][n]);
  }

  __shared__ float S[64][65];
  const float scale = 0.125f;  // 1/sqrt(64)
#pragma unroll
  for (int m = 0; m < 2; ++m)
#pragma unroll
    for (int n = 0; n < 2; ++n)
#pragma unroll
      for (int j = 0; j < 4; ++j)
        S[wm + m * 16 + l4 * 4 + j][wn + n * 16 + l15] = acc[m][n][j] * scale;
  __syncthreads();

  const int r = tid >> 2, seg = (tid & 3) * 16;
  float vals[16];
  float mx = -1e30f;
#pragma unroll
  for (int c = 0; c < 16; ++c) { vals[c] = S[r][seg + c]; mx = fmaxf(mx, vals[c]); }
  mx = fmaxf(mx, __shfl_xor(mx, 1));
  mx = fmaxf(mx, __shfl_xor(mx, 2));
  float sum = 0.f;
#pragma unroll
  for (int c = 0; c < 16; ++c) { vals[c] = __expf(vals[c] - mx); sum += vals[c]; }
  sum += __shfl_xor(sum, 1);
  sum += __shfl_xor(sum, 2);
  const float inv = 1.0f / sum;
  bf16_t* arow = attn + (size_t)bh * 64 * 64 + (size_t)r * 64 + seg;
#pragma unroll
  for (int c = 0; c < 16; ++c) arow[c] = (bf16_t)(vals[c] * inv);
}

// ---------- WvEffT[b][c][h*64+i] = sum_j WvT[h][c][j] * attn[bh][i][j] ----------
// grid (m-blocks of 128 over c, bh); block 256; 4 waves 2x2, wave tile 64x32; K=64
__global__ __launch_bounds__(256)
void k_wveff(const bf16_t* __restrict__ wvT, const bf16_t* __restrict__ attn,
             bf16_t* __restrict__ wveffT) {
  const int bh = blockIdx.y;
  const int b = bh >> 3, h = bh & 7;
  const int tid = threadIdx.x;
  const int wave = tid >> 6, lane = tid & 63;
  const int l15 = lane & 15, l4 = lane >> 4;
  const bf16_t* av = wvT + (size_t)h * 512 * 64;
  const bf16_t* ab = attn + (size_t)bh * 64 * 64;
  bf16_t* ob = wveffT + (size_t)b * 262144 + (size_t)h * 64;
  const int cm0 = blockIdx.x * 128;
  const int wm = (wave >> 1) * 64, wn = (wave & 1) * 32;

  f32x4 acc[4][2] = {};
#pragma unroll
  for (int ks = 0; ks < 2; ++ks) {
    const int k0 = ks * 32;
    bf16x8 af[4], bfr[2];
#pragma unroll
    for (int m = 0; m < 4; ++m)
      af[m] = *(const bf16x8*)(&av[(size_t)(cm0 + wm + m * 16 + l15) * 64 + k0 + l4 * 8]);
#pragma unroll
    for (int n = 0; n < 2; ++n)
      bfr[n] = *(const bf16x8*)(&ab[(wn + n * 16 + l15) * 64 + k0 + l4 * 8]);
#pragma unroll
    for (int m = 0; m < 4; ++m)
#pragma unroll
      for (int n = 0; n < 2; ++n)
        acc[m][n] = MFMA_16x16x32(af[m], bfr[n], acc[m][n]);
  }
#pragma unroll
  for (int m = 0; m < 4; ++m)
#pragma unroll
    for (int n = 0; n < 2; ++n)
#pragma unroll
      for (int j = 0; j < 4; ++j)
        ob[(size_t)(cm0 + wm + m * 16 + l4 * 4 + j) * 512 + wn + n * 16 + l15] =
            (bf16_t)acc[m][n][j];
}

extern "C" void kernel_launch(void* const* d_in, const int* in_sizes, int n_in,
                              void* d_out, int out_size, void* d_ws, size_t ws_size,
                              hipStream_t stream) {
  const float* f_m  = (const float*)d_in[0];
  const float* f_n  = (const float*)d_in[1];
  const float* Wq   = (const float*)d_in[2];
  const float* Wkv  = (const float*)d_in[3];
  const float* Wout = (const float*)d_in[4];
  const float* bout = (const float*)d_in[5];
  float* y = (float*)d_out;

  const size_t ACT = (size_t)8 * 4096 * 512;   // 16.8M elems
  const size_t SQ  = (size_t)512 * 512;        // 262144
  char* p = (char*)d_ws;
  bf16_t* wq_b    = (bf16_t*)p; p += SQ * 2;
  bf16_t* wk_b    = (bf16_t*)p; p += SQ * 2;
  bf16_t* wout_b  = (bf16_t*)p; p += SQ * 2;
  bf16_t* wvT     = (bf16_t*)p; p += SQ * 2;           // [h][c][64]
  bf16_t* attnw   = (bf16_t*)p; p += (size_t)64 * 64 * 64 * 2;
  bf16_t* Hb      = (bf16_t*)p; p += (size_t)8 * SQ * 2;   // [b][c'][c]
  bf16_t* T1      = (bf16_t*)p; p += (size_t)8 * SQ * 2;   // [b][hi][c']
  bf16_t* wveffT  = (bf16_t*)p; p += (size_t)8 * SQ * 2;   // [b][c][hi]
  bf16_t* W2      = (bf16_t*)p; p += (size_t)8 * SQ * 2;   // [b][o][c]
  float*  Hp      = (float*)p;  p += (size_t)32 * SQ * 4;  // split-K partials
  bf16_t* fm_bf   = (bf16_t*)p; p += ACT * 2;              // [b][c][n]
  bf16_t* fn_bf   = (bf16_t*)p; p += ACT * 2;              // [b][c'][n]
  bf16_t* fnT     = (bf16_t*)p; p += ACT * 2;              // [b][n][c]

  // weights
  k_cvt<<<dim3((int)(SQ / 256)), 256, 0, stream>>>(Wq, wq_b, (int)SQ);
  k_cvt<<<dim3((int)(SQ / 256)), 256, 0, stream>>>(Wkv, wk_b, (int)SQ);
  k_cvt<<<dim3((int)(SQ / 256)), 256, 0, stream>>>(Wout, wout_b, (int)SQ);
  k_transpose_cast<<<dim3(16, 2, 8), dim3(32, 8), 0, stream>>>(Wkv + SQ, wvT, 64, 512);

  // activations
  k_cvt4<<<dim3((int)(ACT / 4 / 256)), 256, 0, stream>>>(f_m, fm_bf, (int)(ACT / 4));
  k_prep_fn<<<dim3(128, 16, 8), dim3(32, 8), 0, stream>>>(f_n, fn_bf, fnT, 512, 4096);

  // H[b][c'][c] = sum_n fn[c'][n] fm[c][n]  (split-K=4)
  k_gemm_bt<2><<<dim3(4, 4, 32), 256, 0, stream>>>(fn_bf, fm_bf, Hp, nullptr,
                                                   512, 512, 4096, 4,
                                                   (long long)ACT / 8, (long long)ACT / 8,
                                                   (long long)SQ);
  k_reduce4<<<dim3((int)(8 * SQ / 4 / 256)), 256, 0, stream>>>(Hp, Hb, (int)SQ);

  // T1[b][hi][c'] = sum_c Wq[hi][c] H[b][c'][c]
  k_gemm_bt<1><<<dim3(4, 4, 8), 256, 0, stream>>>(wq_b, Hb, T1, nullptr,
                                                  512, 512, 512, 1,
                                                  0, (long long)SQ, (long long)SQ);
  // dots + softmax -> attn
  k_dots_softmax<<<dim3(64), 256, 0, stream>>>(T1, wk_b, attnw);
  // WvEffT[b][c][hi]
  k_wveff<<<dim3(4, 64), 256, 0, stream>>>(wvT, attnw, wveffT);
  // W2[b][o][c] = sum_hi Wout[o][hi] WvEffT[b][c][hi]
  k_gemm_bt<1><<<dim3(4, 4, 8), 256, 0, stream>>>(wout_b, wveffT, W2, nullptr,
                                                  512, 512, 512, 1,
                                                  0, (long long)SQ, (long long)SQ);
  // y[b][o][n] = sum_c W2[b][o][c] fnT[b][n][c] + bout[o]
  k_gemm_bt<0><<<dim3(32, 4, 8), 256, 0, stream>>>(W2, fnT, y, bout,
                                                   512, 4096, 512, 1,
                                                   (long long)SQ, (long long)ACT / 8,
                                                   (long long)ACT / 8);
}

// Round 5
// 170.380 us; speedup vs baseline: 1.6616x; 1.0931x over previous
//
#include <hip/hip_runtime.h>
#include <hip/hip_bf16.h>
#include <stdint.h>

typedef __bf16 bf16_t;
typedef __bf16 bf16x8 __attribute__((ext_vector_type(8)));
typedef float f32x4 __attribute__((ext_vector_type(4)));

#define MFMA_16x16x32(A, B, C) __builtin_amdgcn_mfma_f32_16x16x32_bf16((A), (B), (C), 0, 0, 0)

__device__ inline void gload_lds16(const bf16_t* g, bf16_t* lds) {
  auto* gp = (const __attribute__((address_space(1))) uint32_t*)(uintptr_t)g;
  auto* lp = (__attribute__((address_space(3))) uint32_t*)(uintptr_t)lds;
  __builtin_amdgcn_global_load_lds(gp, lp, 16, 0, 0);
}

// ---------- fp32 -> bf16 elementwise (scalar, for small weights) ----------
__global__ void k_cvt(const float* __restrict__ in, bf16_t* __restrict__ out, int n) {
  int i = blockIdx.x * blockDim.x + threadIdx.x;
  if (i < n) out[i] = (bf16_t)in[i];
}

// ---------- fp32 -> bf16, 8 elems/thread (16B stores) ----------
__global__ __launch_bounds__(256)
void k_cvt8(const float* __restrict__ in, bf16_t* __restrict__ out, int n8) {
  int i = blockIdx.x * blockDim.x + threadIdx.x;
  if (i < n8) {
    float4 a = ((const float4*)in)[(size_t)i * 2];
    float4 c = ((const float4*)in)[(size_t)i * 2 + 1];
    bf16_t o[8] = {(bf16_t)a.x, (bf16_t)a.y, (bf16_t)a.z, (bf16_t)a.w,
                   (bf16_t)c.x, (bf16_t)c.y, (bf16_t)c.z, (bf16_t)c.w};
    *(uint4*)(out + (size_t)i * 8) = *(uint4*)o;
  }
}

// ---------- transpose + cast: in [C][N] f32 -> out [N][C] bf16, per batch (z) ----------
__global__ __launch_bounds__(256)
void k_transpose_cast(const float* __restrict__ in, bf16_t* __restrict__ out, int C, int N) {
  __shared__ float tile[32][33];
  int b = blockIdx.z;
  const float* src = in + (size_t)b * C * N;
  bf16_t* dst = out + (size_t)b * C * N;
  int n0 = blockIdx.x * 32, c0 = blockIdx.y * 32;
  int tx = threadIdx.x, ty = threadIdx.y;
#pragma unroll
  for (int i = 0; i < 32; i += 8)
    tile[ty + i][tx] = src[(size_t)(c0 + ty + i) * N + (n0 + tx)];
  __syncthreads();
#pragma unroll
  for (int i = 0; i < 32; i += 8)
    dst[(size_t)(n0 + ty + i) * C + (c0 + tx)] = (bf16_t)tile[tx][ty + i];
}

// ---------- f_n prep: read f32 [C][N] -> bf16 [C][N] and bf16 [N][C], 64x64 tiles ----------
// NOTE: 16 bf16 per thread = 32 B -> must be TWO uint4 stores (round-4 bug: one uint4
// stored only half, leaving 0xAA poison in the other half).
__global__ __launch_bounds__(256)
void k_prep_fn(const float* __restrict__ in, bf16_t* __restrict__ out_cn,
               bf16_t* __restrict__ out_nc, int C, int N) {
  __shared__ float tile[64][65];
  const int b = blockIdx.z;
  const float* src = in + (size_t)b * C * N;
  const int n0 = blockIdx.x * 64, c0 = blockIdx.y * 64;
  const int t = threadIdx.x;
  const int cr = t >> 2;            // row 0..63 (channel)
  const int nc = (t & 3) * 16;      // 16-col chunk (spatial)
  {
    const float* srow = src + (size_t)(c0 + cr) * N + n0 + nc;
    bf16_t oc[16];
#pragma unroll
    for (int q = 0; q < 4; ++q) {
      float4 v = *(const float4*)(srow + q * 4);
      tile[cr][nc + q * 4 + 0] = v.x; tile[cr][nc + q * 4 + 1] = v.y;
      tile[cr][nc + q * 4 + 2] = v.z; tile[cr][nc + q * 4 + 3] = v.w;
      oc[q * 4 + 0] = (bf16_t)v.x; oc[q * 4 + 1] = (bf16_t)v.y;
      oc[q * 4 + 2] = (bf16_t)v.z; oc[q * 4 + 3] = (bf16_t)v.w;
    }
    bf16_t* dst = out_cn + (size_t)b * C * N + (size_t)(c0 + cr) * N + n0 + nc;
    *(uint4*)(dst) = *(uint4*)(oc);
    *(uint4*)(dst + 8) = *(uint4*)(oc + 8);
  }
  __syncthreads();
  {
    const int nr = t >> 2;          // spatial row 0..63
    const int cc = (t & 3) * 16;    // 16-channel chunk
    bf16_t on[16];
#pragma unroll
    for (int q = 0; q < 16; ++q) on[q] = (bf16_t)tile[cc + q][nr];
    bf16_t* dst = out_nc + (size_t)b * (size_t)N * C + (size_t)(n0 + nr) * C + c0 + cc;
    *(uint4*)(dst) = *(uint4*)(on);
    *(uint4*)(dst + 8) = *(uint4*)(on + 8);
  }
}

// ---------- C[M][N] = A[M][K] * B[N][K]^T  (bf16 in, fp32 acc), dbuf 2-phase ----------
// 128x128 tile, BK=32, 4 waves (2x2), each wave 64x64 (4x4 frags of 16x16).
// MODE: 0 = f32 out + bias, 1 = bf16 out, 2 = f32 partial (no bias)
template <int MODE>
__global__ __launch_bounds__(256)
void k_gemm_bt(const bf16_t* __restrict__ A, const bf16_t* __restrict__ B,
               void* __restrict__ Cv, const float* __restrict__ bias,
               int M, int N, int K, int KS,
               long long sA, long long sB, long long sC) {
  const int zb = blockIdx.z;
  const int b = zb / KS, ks = zb - b * KS;
  A += (size_t)b * sA;
  B += (size_t)b * sB;
  const int klen = K / KS;
  const int kbeg = ks * klen;

  const int tid = threadIdx.x;
  const int wave = tid >> 6, lane = tid & 63;
  const int l15 = lane & 15, l4 = lane >> 4;
  const int bm = blockIdx.y * 128, bn = blockIdx.x * 128;
  const int wm = (wave >> 1) * 64, wn = (wave & 1) * 64;

  __shared__ bf16_t As[2][128 * 32];
  __shared__ bf16_t Bs[2][128 * 32];

  f32x4 acc[4][4] = {};

  const int lrow = lane >> 2;        // 0..15 within wave
  const int lchunk = (lane & 3) * 8; // elem offset within BK=32
  const int ra = wave * 16 + lrow;

  auto stage = [&](int buf, int k0) {
    gload_lds16(&A[(size_t)(bm + ra) * K + k0 + lchunk],      &As[buf][(wave * 16) * 32]);
    gload_lds16(&A[(size_t)(bm + 64 + ra) * K + k0 + lchunk], &As[buf][(64 + wave * 16) * 32]);
    gload_lds16(&B[(size_t)(bn + ra) * K + k0 + lchunk],      &Bs[buf][(wave * 16) * 32]);
    gload_lds16(&B[(size_t)(bn + 64 + ra) * K + k0 + lchunk], &Bs[buf][(64 + wave * 16) * 32]);
  };

  const int nsteps = klen / 32;
  stage(0, kbeg);
  __syncthreads();  // drains vmcnt(0) before barrier (compiler-inserted)

  for (int i = 0; i < nsteps; ++i) {
    const int cur = i & 1;
    if (i + 1 < nsteps) stage(cur ^ 1, kbeg + (i + 1) * 32);  // async into other buf
    bf16x8 af[4], bfr[4];
#pragma unroll
    for (int m = 0; m < 4; ++m)
      af[m] = *(const bf16x8*)(&As[cur][(wm + m * 16 + l15) * 32 + l4 * 8]);
#pragma unroll
    for (int n = 0; n < 4; ++n)
      bfr[n] = *(const bf16x8*)(&Bs[cur][(wn + n * 16 + l15) * 32 + l4 * 8]);
#pragma unroll
    for (int m = 0; m < 4; ++m)
#pragma unroll
      for (int n = 0; n < 4; ++n)
        acc[m][n] = MFMA_16x16x32(af[m], bfr[n], acc[m][n]);
    __syncthreads();  // next buf staged + all waves done reading cur
  }

#pragma unroll
  for (int m = 0; m < 4; ++m) {
    const int row0 = bm + wm + m * 16 + l4 * 4;
#pragma unroll
    for (int n = 0; n < 4; ++n) {
      const int col = bn + wn + n * 16 + l15;
#pragma unroll
      for (int j = 0; j < 4; ++j) {
        float v = acc[m][n][j];
        if (MODE == 1) {
          ((bf16_t*)Cv + (size_t)zb * sC)[(size_t)(row0 + j) * N + col] = (bf16_t)v;
        } else if (MODE == 0) {
          ((float*)Cv + (size_t)zb * sC)[(size_t)(row0 + j) * N + col] = v + bias[row0 + j];
        } else {
          ((float*)Cv + (size_t)zb * sC)[(size_t)(row0 + j) * N + col] = v;
        }
      }
    }
  }
}

// ---------- reduce 4 split-K partials -> bf16 ----------
__global__ __launch_bounds__(256)
void k_reduce4(const float* __restrict__ p, bf16_t* __restrict__ out, int per_b) {
  int i = blockIdx.x * blockDim.x + threadIdx.x;
  int nt4 = per_b / 4;
  int b = i / nt4, e4 = (i - b * nt4) * 4;
  const float* pb = p + (size_t)b * 4 * per_b + e4;
  float4 s = *(const float4*)(pb);
#pragma unroll
  for (int ks = 1; ks < 4; ++ks) {
    float4 v = *(const float4*)(pb + (size_t)ks * per_b);
    s.x += v.x; s.y += v.y; s.z += v.z; s.w += v.w;
  }
  bf16_t o[4] = {(bf16_t)s.x, (bf16_t)s.y, (bf16_t)s.z, (bf16_t)s.w};
  *(uint2*)(out + (size_t)b * per_b + e4) = *(uint2*)o;
}

// ---------- dots + softmax: one block per (b,h) ----------
__global__ __launch_bounds__(256)
void k_dots_softmax(const bf16_t* __restrict__ T1, const bf16_t* __restrict__ wk,
                    bf16_t* __restrict__ attn) {
  const int bh = blockIdx.x;
  const bf16_t* qh = T1 + (size_t)(bh >> 3) * 262144 + (size_t)(bh & 7) * 64 * 512;
  const bf16_t* kh = wk + (size_t)(bh & 7) * 64 * 512;
  const int tid = threadIdx.x;
  const int wave = tid >> 6, lane = tid & 63;
  const int l15 = lane & 15, l4 = lane >> 4;
  const int wm = (wave >> 1) * 32, wn = (wave & 1) * 32;

  f32x4 acc[2][2] = {};
#pragma unroll 2
  for (int k0 = 0; k0 < 512; k0 += 32) {
    bf16x8 af[2], bfr[2];
#pragma unroll
    for (int m = 0; m < 2; ++m)
      af[m] = *(const bf16x8*)(&qh[(size_t)(wm + m * 16 + l15) * 512 + k0 + l4 * 8]);
#pragma unroll
    for (int n = 0; n < 2; ++n)
      bfr[n] = *(const bf16x8*)(&kh[(size_t)(wn + n * 16 + l15) * 512 + k0 + l4 * 8]);
#pragma unroll
    for (int m = 0; m < 2; ++m)
#pragma unroll
      for (int n = 0; n < 2; ++n)
        acc[m][n] = MFMA_16x16x32(af[m], bfr[n], acc[m][n]);
  }

  __shared__ float S[64][65];
  const float scale = 0.125f;
#pragma unroll
  for (int m = 0; m < 2; ++m)
#pragma unroll
    for (int n = 0; n < 2; ++n)
#pragma unroll
      for (int j = 0; j < 4; ++j)
        S[wm + m * 16 + l4 * 4 + j][wn + n * 16 + l15] = acc[m][n][j] * scale;
  __syncthreads();

  const int r = tid >> 2, seg = (tid & 3) * 16;
  float vals[16];
  float mx = -1e30f;
#pragma unroll
  for (int c = 0; c < 16; ++c) { vals[c] = S[r][seg + c]; mx = fmaxf(mx, vals[c]); }
  mx = fmaxf(mx, __shfl_xor(mx, 1));
  mx = fmaxf(mx, __shfl_xor(mx, 2));
  float sum = 0.f;
#pragma unroll
  for (int c = 0; c < 16; ++c) { vals[c] = __expf(vals[c] - mx); sum += vals[c]; }
  sum += __shfl_xor(sum, 1);
  sum += __shfl_xor(sum, 2);
  const float inv = 1.0f / sum;
  bf16_t* arow = attn + (size_t)bh * 64 * 64 + (size_t)r * 64 + seg;
#pragma unroll
  for (int c = 0; c < 16; ++c) arow[c] = (bf16_t)(vals[c] * inv);
}

// ---------- WvEffT[b][c][h*64+i] = sum_j WvT[h][c][j] * attn[bh][i][j] ----------
__global__ __launch_bounds__(256)
void k_wveff(const bf16_t* __restrict__ wvT, const bf16_t* __restrict__ attn,
             bf16_t* __restrict__ wveffT) {
  const int bh = blockIdx.y;
  const int b = bh >> 3, h = bh & 7;
  const int tid = threadIdx.x;
  const int wave = tid >> 6, lane = tid & 63;
  const int l15 = lane & 15, l4 = lane >> 4;
  const bf16_t* av = wvT + (size_t)h * 512 * 64;
  const bf16_t* ab = attn + (size_t)bh * 64 * 64;
  bf16_t* ob = wveffT + (size_t)b * 262144 + (size_t)h * 64;
  const int cm0 = blockIdx.x * 128;
  const int wm = (wave >> 1) * 64, wn = (wave & 1) * 32;

  f32x4 acc[4][2] = {};
#pragma unroll
  for (int ks = 0; ks < 2; ++ks) {
    const int k0 = ks * 32;
    bf16x8 af[4], bfr[2];
#pragma unroll
    for (int m = 0; m < 4; ++m)
      af[m] = *(const bf16x8*)(&av[(size_t)(cm0 + wm + m * 16 + l15) * 64 + k0 + l4 * 8]);
#pragma unroll
    for (int n = 0; n < 2; ++n)
      bfr[n] = *(const bf16x8*)(&ab[(wn + n * 16 + l15) * 64 + k0 + l4 * 8]);
#pragma unroll
    for (int m = 0; m < 4; ++m)
#pragma unroll
      for (int n = 0; n < 2; ++n)
        acc[m][n] = MFMA_16x16x32(af[m], bfr[n], acc[m][n]);
  }
#pragma unroll
  for (int m = 0; m < 4; ++m)
#pragma unroll
    for (int n = 0; n < 2; ++n)
#pragma unroll
      for (int j = 0; j < 4; ++j)
        ob[(size_t)(cm0 + wm + m * 16 + l4 * 4 + j) * 512 + wn + n * 16 + l15] =
            (bf16_t)acc[m][n][j];
}

extern "C" void kernel_launch(void* const* d_in, const int* in_sizes, int n_in,
                              void* d_out, int out_size, void* d_ws, size_t ws_size,
                              hipStream_t stream) {
  const float* f_m  = (const float*)d_in[0];
  const float* f_n  = (const float*)d_in[1];
  const float* Wq   = (const float*)d_in[2];
  const float* Wkv  = (const float*)d_in[3];
  const float* Wout = (const float*)d_in[4];
  const float* bout = (const float*)d_in[5];
  float* y = (float*)d_out;

  const size_t ACT = (size_t)8 * 4096 * 512;   // 16.8M elems
  const size_t SQ  = (size_t)512 * 512;
  char* p = (char*)d_ws;
  bf16_t* wq_b    = (bf16_t*)p; p += SQ * 2;
  bf16_t* wk_b    = (bf16_t*)p; p += SQ * 2;
  bf16_t* wout_b  = (bf16_t*)p; p += SQ * 2;
  bf16_t* wvT     = (bf16_t*)p; p += SQ * 2;           // [h][c][64]
  bf16_t* attnw   = (bf16_t*)p; p += (size_t)64 * 64 * 64 * 2;
  bf16_t* Hb      = (bf16_t*)p; p += (size_t)8 * SQ * 2;   // [b][c'][c]
  bf16_t* T1      = (bf16_t*)p; p += (size_t)8 * SQ * 2;   // [b][hi][c']
  bf16_t* wveffT  = (bf16_t*)p; p += (size_t)8 * SQ * 2;   // [b][c][hi]
  bf16_t* W2      = (bf16_t*)p; p += (size_t)8 * SQ * 2;   // [b][o][c]
  float*  Hp      = (float*)p;  p += (size_t)32 * SQ * 4;  // split-K partials
  bf16_t* fm_bf   = (bf16_t*)p; p += ACT * 2;              // [b][c][n]
  bf16_t* fn_bf   = (bf16_t*)p; p += ACT * 2;              // [b][c'][n]
  bf16_t* fnT     = (bf16_t*)p; p += ACT * 2;              // [b][n][c]

  // weights
  k_cvt<<<dim3((int)(SQ / 256)), 256, 0, stream>>>(Wq, wq_b, (int)SQ);
  k_cvt<<<dim3((int)(SQ / 256)), 256, 0, stream>>>(Wkv, wk_b, (int)SQ);
  k_cvt<<<dim3((int)(SQ / 256)), 256, 0, stream>>>(Wout, wout_b, (int)SQ);
  k_transpose_cast<<<dim3(16, 2, 8), dim3(32, 8), 0, stream>>>(Wkv + SQ, wvT, 64, 512);

  // activations
  k_cvt8<<<dim3((int)(ACT / 8 / 256)), 256, 0, stream>>>(f_m, fm_bf, (int)(ACT / 8));
  k_prep_fn<<<dim3(64, 8, 8), 256, 0, stream>>>(f_n, fn_bf, fnT, 512, 4096);

  // H[b][c'][c] = sum_n fn[c'][n] fm[c][n]  (split-K=4)
  k_gemm_bt<2><<<dim3(4, 4, 32), 256, 0, stream>>>(fn_bf, fm_bf, Hp, nullptr,
                                                   512, 512, 4096, 4,
                                                   (long long)ACT / 8, (long long)ACT / 8,
                                                   (long long)SQ);
  k_reduce4<<<dim3((int)(8 * SQ / 4 / 256)), 256, 0, stream>>>(Hp, Hb, (int)SQ);

  // T1[b][hi][c'] = sum_c Wq[hi][c] H[b][c'][c]
  k_gemm_bt<1><<<dim3(4, 4, 8), 256, 0, stream>>>(wq_b, Hb, T1, nullptr,
                                                  512, 512, 512, 1,
                                                  0, (long long)SQ, (long long)SQ);
  // dots + softmax -> attn
  k_dots_softmax<<<dim3(64), 256, 0, stream>>>(T1, wk_b, attnw);
  // WvEffT[b][c][hi]
  k_wveff<<<dim3(4, 64), 256, 0, stream>>>(wvT, attnw, wveffT);
  // W2[b][o][c] = sum_hi Wout[o][hi] WvEffT[b][c][hi]
  k_gemm_bt<1><<<dim3(4, 4, 8), 256, 0, stream>>>(wout_b, wveffT, W2, nullptr,
                                                  512, 512, 512, 1,
                                                  0, (long long)SQ, (long long)SQ);
  // y[b][o][n] = sum_c W2[b][o][c] fnT[b][n][c] + bout[o]
  k_gemm_bt<0><<<dim3(32, 4, 8), 256, 0, stream>>>(W2, fnT, y, bout,
                                                   512, 4096, 512, 1,
                                                   (long long)SQ, (long long)ACT / 8,
                                                   (long long)ACT / 8);
}

// Round 6
// 164.300 us; speedup vs baseline: 1.7231x; 1.0370x over previous
//
#include <hip/hip_runtime.h>
#include <hip/hip_bf16.h>
#include <stdint.h>

typedef __bf16 bf16_t;
typedef __bf16 bf16x8 __attribute__((ext_vector_type(8)));
typedef float f32x4 __attribute__((ext_vector_type(4)));

#define MFMA_16x16x32(A, B, C) __builtin_amdgcn_mfma_f32_16x16x32_bf16((A), (B), (C), 0, 0, 0)

__device__ inline void gload_lds16(const bf16_t* g, bf16_t* lds) {
  auto* gp = (const __attribute__((address_space(1))) uint32_t*)(uintptr_t)g;
  auto* lp = (__attribute__((address_space(3))) uint32_t*)(uintptr_t)lds;
  __builtin_amdgcn_global_load_lds(gp, lp, 16, 0, 0);
}

// ---------- fp32 -> bf16 elementwise (small weights) ----------
__global__ void k_cvt(const float* __restrict__ in, bf16_t* __restrict__ out, int n) {
  int i = blockIdx.x * blockDim.x + threadIdx.x;
  if (i < n) out[i] = (bf16_t)in[i];
}

// ---------- transpose + cast: in [C][N] f32 -> out [N][C] bf16, per batch (z) ----------
__global__ __launch_bounds__(256)
void k_transpose_cast(const float* __restrict__ in, bf16_t* __restrict__ out, int C, int N) {
  __shared__ float tile[32][33];
  int b = blockIdx.z;
  const float* src = in + (size_t)b * C * N;
  bf16_t* dst = out + (size_t)b * C * N;
  int n0 = blockIdx.x * 32, c0 = blockIdx.y * 32;
  int tx = threadIdx.x, ty = threadIdx.y;
#pragma unroll
  for (int i = 0; i < 32; i += 8)
    tile[ty + i][tx] = src[(size_t)(c0 + ty + i) * N + (n0 + tx)];
  __syncthreads();
#pragma unroll
  for (int i = 0; i < 32; i += 8)
    dst[(size_t)(n0 + ty + i) * C + (c0 + tx)] = (bf16_t)tile[tx][ty + i];
}

// ---------- f_n -> fnT only: read f32 [C][N], write bf16 [N][C], 64x64 tiles ----------
// (16 bf16 per thread = 32 B -> TWO uint4 stores; round-4 lesson)
__global__ __launch_bounds__(256)
void k_fnT(const float* __restrict__ in, bf16_t* __restrict__ out_nc, int C, int N) {
  __shared__ float tile[64][65];
  const int b = blockIdx.z;
  const float* src = in + (size_t)b * C * N;
  const int n0 = blockIdx.x * 64, c0 = blockIdx.y * 64;
  const int t = threadIdx.x;
  const int cr = t >> 2;            // channel row 0..63
  const int nc = (t & 3) * 16;      // 16-col chunk (spatial)
  {
    const float* srow = src + (size_t)(c0 + cr) * N + n0 + nc;
#pragma unroll
    for (int q = 0; q < 4; ++q) {
      float4 v = *(const float4*)(srow + q * 4);
      tile[cr][nc + q * 4 + 0] = v.x; tile[cr][nc + q * 4 + 1] = v.y;
      tile[cr][nc + q * 4 + 2] = v.z; tile[cr][nc + q * 4 + 3] = v.w;
    }
  }
  __syncthreads();
  {
    const int nr = t >> 2;          // spatial row 0..63
    const int cc = (t & 3) * 16;    // 16-channel chunk
    bf16_t on[16];
#pragma unroll
    for (int q = 0; q < 16; ++q) on[q] = (bf16_t)tile[cc + q][nr];
    bf16_t* dst = out_nc + (size_t)b * (size_t)N * C + (size_t)(n0 + nr) * C + c0 + cc;
    *(uint4*)(dst) = *(uint4*)(on);
    *(uint4*)(dst + 8) = *(uint4*)(on + 8);
  }
}

// ---------- H partials from f32 inputs: Hp[zb][c'][c], zb = b*8+ks ----------
// A=f_n [b][512][4096] f32 (rows = c'), B=f_m (rows = c), contract over n.
// 128x128 tile, BK=32, reg-staged f32->bf16 cvt, split-K=8, bf16 partial out.
__global__ __launch_bounds__(256)
void k_gram(const float* __restrict__ A, const float* __restrict__ B,
            bf16_t* __restrict__ Cp) {
  // XCD swizzle over 1024 blocks (1024 % 8 == 0 -> m157 form is bijective)
  int lin = blockIdx.x + 4 * blockIdx.y + 16 * blockIdx.z;
  lin = (lin & 7) * 128 + (lin >> 3);
  const int nt = lin & 3, mt = (lin >> 2) & 3, zb = lin >> 4;
  const int b = zb >> 3, ks = zb & 7;
  const float* Ab = A + (size_t)b * 512 * 4096;
  const float* Bb = B + (size_t)b * 512 * 4096;
  const int bm = mt * 128, bn = nt * 128;
  const int kbeg = ks * 512;     // klen = 512 -> 16 steps of BK=32

  const int tid = threadIdx.x;
  const int wave = tid >> 6, lane = tid & 63;
  const int l15 = lane & 15, l4 = lane >> 4;
  const int wm = (wave >> 1) * 64, wn = (wave & 1) * 64;

  __shared__ bf16_t As[128 * 32];
  __shared__ bf16_t Bs[128 * 32];

  f32x4 acc[4][4] = {};

  const int srow = tid >> 1;        // 0..127
  const int scol = (tid & 1) * 16;  // 0 or 16 (f32 elems within BK=32)
  const float* ga = Ab + (size_t)(bm + srow) * 4096 + kbeg + scol;
  const float* gb = Bb + (size_t)(bn + srow) * 4096 + kbeg + scol;

  float4 ra[4], rb[4];
#pragma unroll
  for (int q = 0; q < 4; ++q) {
    ra[q] = *(const float4*)(ga + q * 4);
    rb[q] = *(const float4*)(gb + q * 4);
  }

  for (int i = 0; i < 16; ++i) {
    if (i) __syncthreads();   // prev step's LDS readers done
    bf16_t ta[16], tb[16];
#pragma unroll
    for (int q = 0; q < 4; ++q) {
      ta[q * 4 + 0] = (bf16_t)ra[q].x; ta[q * 4 + 1] = (bf16_t)ra[q].y;
      ta[q * 4 + 2] = (bf16_t)ra[q].z; ta[q * 4 + 3] = (bf16_t)ra[q].w;
      tb[q * 4 + 0] = (bf16_t)rb[q].x; tb[q * 4 + 1] = (bf16_t)rb[q].y;
      tb[q * 4 + 2] = (bf16_t)rb[q].z; tb[q * 4 + 3] = (bf16_t)rb[q].w;
    }
    *(uint4*)(&As[srow * 32 + scol]) = *(uint4*)(ta);
    *(uint4*)(&As[srow * 32 + scol + 8]) = *(uint4*)(ta + 8);
    *(uint4*)(&Bs[srow * 32 + scol]) = *(uint4*)(tb);
    *(uint4*)(&Bs[srow * 32 + scol + 8]) = *(uint4*)(tb + 8);
    if (i + 1 < 16) {  // issue next loads; in flight across barrier + MFMA
      const float* na = ga + (i + 1) * 32;
      const float* nb = gb + (i + 1) * 32;
#pragma unroll
      for (int q = 0; q < 4; ++q) {
        ra[q] = *(const float4*)(na + q * 4);
        rb[q] = *(const float4*)(nb + q * 4);
      }
    }
    __syncthreads();
    bf16x8 af[4], bfr[4];
#pragma unroll
    for (int m = 0; m < 4; ++m)
      af[m] = *(const bf16x8*)(&As[(wm + m * 16 + l15) * 32 + l4 * 8]);
#pragma unroll
    for (int n = 0; n < 4; ++n)
      bfr[n] = *(const bf16x8*)(&Bs[(wn + n * 16 + l15) * 32 + l4 * 8]);
#pragma unroll
    for (int m = 0; m < 4; ++m)
#pragma unroll
      for (int n = 0; n < 4; ++n)
        acc[m][n] = MFMA_16x16x32(af[m], bfr[n], acc[m][n]);
  }

  bf16_t* Cb = Cp + (size_t)zb * 262144;
#pragma unroll
  for (int m = 0; m < 4; ++m) {
    const int row0 = wm + m * 16 + l4 * 4;
#pragma unroll
    for (int n = 0; n < 4; ++n) {
      const int col = bn + wn + n * 16 + l15;
#pragma unroll
      for (int j = 0; j < 4; ++j)
        Cb[(size_t)(bm + row0 + j) * 512 + col] = (bf16_t)acc[m][n][j];
    }
  }
}

// ---------- reduce 8 bf16 split-K partials -> bf16 ----------
__global__ __launch_bounds__(256)
void k_reduce8(const bf16_t* __restrict__ p, bf16_t* __restrict__ out) {
  int i = blockIdx.x * blockDim.x + threadIdx.x;  // 262144 threads total
  int b = i >> 15;                 // 32768 threads per batch (SQ/8)
  int e8 = (i & 32767) * 8;
  const bf16_t* pb = p + (size_t)b * 8 * 262144 + e8;
  float s[8] = {};
#pragma unroll
  for (int ks = 0; ks < 8; ++ks) {
    bf16x8 v = *(const bf16x8*)(pb + (size_t)ks * 262144);
#pragma unroll
    for (int j = 0; j < 8; ++j) s[j] += (float)v[j];
  }
  bf16x8 o;
#pragma unroll
  for (int j = 0; j < 8; ++j) o[j] = (bf16_t)s[j];
  *(bf16x8*)(out + (size_t)b * 262144 + e8) = o;
}

// ---------- C[M][N] = A[M][K] * B[N][K]^T  (bf16 in, fp32 acc), dbuf 2-phase ----------
// MODE: 0 = f32 out + bias, 1 = bf16 out
template <int MODE>
__global__ __launch_bounds__(256)
void k_gemm_bt(const bf16_t* __restrict__ A, const bf16_t* __restrict__ B,
               void* __restrict__ Cv, const float* __restrict__ bias,
               int M, int N, int K, int KS,
               long long sA, long long sB, long long sC) {
  const int zb = blockIdx.z;
  const int b = zb / KS, ks = zb - b * KS;
  A += (size_t)b * sA;
  B += (size_t)b * sB;
  const int klen = K / KS;
  const int kbeg = ks * klen;

  const int tid = threadIdx.x;
  const int wave = tid >> 6, lane = tid & 63;
  const int l15 = lane & 15, l4 = lane >> 4;
  const int bm = blockIdx.y * 128, bn = blockIdx.x * 128;
  const int wm = (wave >> 1) * 64, wn = (wave & 1) * 64;

  __shared__ bf16_t As[2][128 * 32];
  __shared__ bf16_t Bs[2][128 * 32];

  f32x4 acc[4][4] = {};

  const int lrow = lane >> 2;
  const int lchunk = (lane & 3) * 8;
  const int ra = wave * 16 + lrow;

  auto stage = [&](int buf, int k0) {
    gload_lds16(&A[(size_t)(bm + ra) * K + k0 + lchunk],      &As[buf][(wave * 16) * 32]);
    gload_lds16(&A[(size_t)(bm + 64 + ra) * K + k0 + lchunk], &As[buf][(64 + wave * 16) * 32]);
    gload_lds16(&B[(size_t)(bn + ra) * K + k0 + lchunk],      &Bs[buf][(wave * 16) * 32]);
    gload_lds16(&B[(size_t)(bn + 64 + ra) * K + k0 + lchunk], &Bs[buf][(64 + wave * 16) * 32]);
  };

  const int nsteps = klen / 32;
  stage(0, kbeg);
  __syncthreads();

  for (int i = 0; i < nsteps; ++i) {
    const int cur = i & 1;
    if (i + 1 < nsteps) stage(cur ^ 1, kbeg + (i + 1) * 32);
    bf16x8 af[4], bfr[4];
#pragma unroll
    for (int m = 0; m < 4; ++m)
      af[m] = *(const bf16x8*)(&As[cur][(wm + m * 16 + l15) * 32 + l4 * 8]);
#pragma unroll
    for (int n = 0; n < 4; ++n)
      bfr[n] = *(const bf16x8*)(&Bs[cur][(wn + n * 16 + l15) * 32 + l4 * 8]);
#pragma unroll
    for (int m = 0; m < 4; ++m)
#pragma unroll
      for (int n = 0; n < 4; ++n)
        acc[m][n] = MFMA_16x16x32(af[m], bfr[n], acc[m][n]);
    __syncthreads();
  }

#pragma unroll
  for (int m = 0; m < 4; ++m) {
    const int row0 = bm + wm + m * 16 + l4 * 4;
#pragma unroll
    for (int n = 0; n < 4; ++n) {
      const int col = bn + wn + n * 16 + l15;
#pragma unroll
      for (int j = 0; j < 4; ++j) {
        float v = acc[m][n][j];
        if (MODE == 1) {
          ((bf16_t*)Cv + (size_t)zb * sC)[(size_t)(row0 + j) * N + col] = (bf16_t)v;
        } else {
          ((float*)Cv + (size_t)zb * sC)[(size_t)(row0 + j) * N + col] = v + bias[row0 + j];
        }
      }
    }
  }
}

// ---------- dots + softmax: one block per (b,h) ----------
__global__ __launch_bounds__(256)
void k_dots_softmax(const bf16_t* __restrict__ T1, const bf16_t* __restrict__ wk,
                    bf16_t* __restrict__ attn) {
  const int bh = blockIdx.x;
  const bf16_t* qh = T1 + (size_t)(bh >> 3) * 262144 + (size_t)(bh & 7) * 64 * 512;
  const bf16_t* kh = wk + (size_t)(bh & 7) * 64 * 512;
  const int tid = threadIdx.x;
  const int wave = tid >> 6, lane = tid & 63;
  const int l15 = lane & 15, l4 = lane >> 4;
  const int wm = (wave >> 1) * 32, wn = (wave & 1) * 32;

  f32x4 acc[2][2] = {};
#pragma unroll 2
  for (int k0 = 0; k0 < 512; k0 += 32) {
    bf16x8 af[2], bfr[2];
#pragma unroll
    for (int m = 0; m < 2; ++m)
      af[m] = *(const bf16x8*)(&qh[(size_t)(wm + m * 16 + l15) * 512 + k0 + l4 * 8]);
#pragma unroll
    for (int n = 0; n < 2; ++n)
      bfr[n] = *(const bf16x8*)(&kh[(size_t)(wn + n * 16 + l15) * 512 + k0 + l4 * 8]);
#pragma unroll
    for (int m = 0; m < 2; ++m)
#pragma unroll
      for (int n = 0; n < 2; ++n)
        acc[m][n] = MFMA_16x16x32(af[m], bfr[n], acc[m][n]);
  }

  __shared__ float S[64][65];
  const float scale = 0.125f;
#pragma unroll
  for (int m = 0; m < 2; ++m)
#pragma unroll
    for (int n = 0; n < 2; ++n)
#pragma unroll
      for (int j = 0; j < 4; ++j)
        S[wm + m * 16 + l4 * 4 + j][wn + n * 16 + l15] = acc[m][n][j] * scale;
  __syncthreads();

  const int r = tid >> 2, seg = (tid & 3) * 16;
  float vals[16];
  float mx = -1e30f;
#pragma unroll
  for (int c = 0; c < 16; ++c) { vals[c] = S[r][seg + c]; mx = fmaxf(mx, vals[c]); }
  mx = fmaxf(mx, __shfl_xor(mx, 1));
  mx = fmaxf(mx, __shfl_xor(mx, 2));
  float sum = 0.f;
#pragma unroll
  for (int c = 0; c < 16; ++c) { vals[c] = __expf(vals[c] - mx); sum += vals[c]; }
  sum += __shfl_xor(sum, 1);
  sum += __shfl_xor(sum, 2);
  const float inv = 1.0f / sum;
  bf16_t* arow = attn + (size_t)bh * 64 * 64 + (size_t)r * 64 + seg;
#pragma unroll
  for (int c = 0; c < 16; ++c) arow[c] = (bf16_t)(vals[c] * inv);
}

// ---------- WvEffT[b][c][h*64+i] = sum_j WvT[h][c][j] * attn[bh][i][j] ----------
__global__ __launch_bounds__(256)
void k_wveff(const bf16_t* __restrict__ wvT, const bf16_t* __restrict__ attn,
             bf16_t* __restrict__ wveffT) {
  const int bh = blockIdx.y;
  const int b = bh >> 3, h = bh & 7;
  const int tid = threadIdx.x;
  const int wave = tid >> 6, lane = tid & 63;
  const int l15 = lane & 15, l4 = lane >> 4;
  const bf16_t* av = wvT + (size_t)h * 512 * 64;
  const bf16_t* ab = attn + (size_t)bh * 64 * 64;
  bf16_t* ob = wveffT + (size_t)b * 262144 + (size_t)h * 64;
  const int cm0 = blockIdx.x * 128;
  const int wm = (wave >> 1) * 64, wn = (wave & 1) * 32;

  f32x4 acc[4][2] = {};
#pragma unroll
  for (int ks = 0; ks < 2; ++ks) {
    const int k0 = ks * 32;
    bf16x8 af[4], bfr[2];
#pragma unroll
    for (int m = 0; m < 4; ++m)
      af[m] = *(const bf16x8*)(&av[(size_t)(cm0 + wm + m * 16 + l15) * 64 + k0 + l4 * 8]);
#pragma unroll
    for (int n = 0; n < 2; ++n)
      bfr[n] = *(const bf16x8*)(&ab[(wn + n * 16 + l15) * 64 + k0 + l4 * 8]);
#pragma unroll
    for (int m = 0; m < 4; ++m)
#pragma unroll
      for (int n = 0; n < 2; ++n)
        acc[m][n] = MFMA_16x16x32(af[m], bfr[n], acc[m][n]);
  }
#pragma unroll
  for (int m = 0; m < 4; ++m)
#pragma unroll
    for (int n = 0; n < 2; ++n)
#pragma unroll
      for (int j = 0; j < 4; ++j)
        ob[(size_t)(cm0 + wm + m * 16 + l4 * 4 + j) * 512 + wn + n * 16 + l15] =
            (bf16_t)acc[m][n][j];
}

extern "C" void kernel_launch(void* const* d_in, const int* in_sizes, int n_in,
                              void* d_out, int out_size, void* d_ws, size_t ws_size,
                              hipStream_t stream) {
  const float* f_m  = (const float*)d_in[0];
  const float* f_n  = (const float*)d_in[1];
  const float* Wq   = (const float*)d_in[2];
  const float* Wkv  = (const float*)d_in[3];
  const float* Wout = (const float*)d_in[4];
  const float* bout = (const float*)d_in[5];
  float* y = (float*)d_out;

  const size_t ACT = (size_t)8 * 4096 * 512;
  const size_t SQ  = (size_t)512 * 512;
  char* p = (char*)d_ws;
  bf16_t* wq_b    = (bf16_t*)p; p += SQ * 2;
  bf16_t* wk_b    = (bf16_t*)p; p += SQ * 2;
  bf16_t* wout_b  = (bf16_t*)p; p += SQ * 2;
  bf16_t* wvT     = (bf16_t*)p; p += SQ * 2;               // [h][c][64]
  bf16_t* attnw   = (bf16_t*)p; p += (size_t)64 * 64 * 64 * 2;
  bf16_t* Hb      = (bf16_t*)p; p += (size_t)8 * SQ * 2;   // [b][c'][c]
  bf16_t* T1      = (bf16_t*)p; p += (size_t)8 * SQ * 2;   // [b][hi][c']
  bf16_t* wveffT  = (bf16_t*)p; p += (size_t)8 * SQ * 2;   // [b][c][hi]
  bf16_t* W2      = (bf16_t*)p; p += (size_t)8 * SQ * 2;   // [b][o][c]
  bf16_t* Hp8     = (bf16_t*)p; p += (size_t)64 * SQ * 2;  // bf16 split-8 partials
  bf16_t* fnT     = (bf16_t*)p; p += ACT * 2;              // [b][n][c]

  // weights
  k_cvt<<<dim3((int)(SQ / 256)), 256, 0, stream>>>(Wq, wq_b, (int)SQ);
  k_cvt<<<dim3((int)(SQ / 256)), 256, 0, stream>>>(Wkv, wk_b, (int)SQ);
  k_cvt<<<dim3((int)(SQ / 256)), 256, 0, stream>>>(Wout, wout_b, (int)SQ);
  k_transpose_cast<<<dim3(16, 2, 8), dim3(32, 8), 0, stream>>>(Wkv + SQ, wvT, 64, 512);

  // fnT first (f_n then L3-warm for k_gram)
  k_fnT<<<dim3(64, 8, 8), 256, 0, stream>>>(f_n, fnT, 512, 4096);

  // H from f32 inputs directly (fused cvt), split-K=8, bf16 partials
  k_gram<<<dim3(4, 4, 64), 256, 0, stream>>>(f_n, f_m, Hp8);
  k_reduce8<<<dim3(1024), 256, 0, stream>>>(Hp8, Hb);

  // T1[b][hi][c'] = sum_c Wq[hi][c] H[b][c'][c]
  k_gemm_bt<1><<<dim3(4, 4, 8), 256, 0, stream>>>(wq_b, Hb, T1, nullptr,
                                                  512, 512, 512, 1,
                                                  0, (long long)SQ, (long long)SQ);
  // dots + softmax -> attn
  k_dots_softmax<<<dim3(64), 256, 0, stream>>>(T1, wk_b, attnw);
  // WvEffT[b][c][hi]
  k_wveff<<<dim3(4, 64), 256, 0, stream>>>(wvT, attnw, wveffT);
  // W2[b][o][c] = sum_hi Wout[o][hi] WvEffT[b][c][hi]
  k_gemm_bt<1><<<dim3(4, 4, 8), 256, 0, stream>>>(wout_b, wveffT, W2, nullptr,
                                                  512, 512, 512, 1,
                                                  0, (long long)SQ, (long long)SQ);
  // y[b][o][n] = sum_c W2[b][o][c] fnT[b][n][c] + bout[o]
  k_gemm_bt<0><<<dim3(32, 4, 8), 256, 0, stream>>>(W2, fnT, y, bout,
                                                   512, 4096, 512, 1,
                                                   (long long)SQ, (long long)ACT / 8,
                                                   (long long)ACT / 8);
}